// Round 6
// baseline (276.355 us; speedup 1.0000x reference)
//
#include <hip/hip_runtime.h>

#define NFEAT 128

typedef __attribute__((ext_vector_type(8))) short bf16x8;
typedef __attribute__((ext_vector_type(4))) float f32x4;

__device__ inline ushort f2b(float v) {  // fp32 -> bf16 RNE
  unsigned u = __builtin_bit_cast(unsigned, v);
  return (ushort)((u + 0x7FFFu + ((u >> 16) & 1u)) >> 16);
}

// shared agg inner loop: unroll-4 over padded CSR segment (pads are (0, w=0.0))
__device__ inline void agg_accum(const ushort* __restrict__ h,
                                 const int2* __restrict__ csr2, int e, int end, int c,
                                 float& a0, float& a1, float& a2, float& a3) {
  for (; e < end; e += 4) {
    int4 q0 = *(const int4*)(csr2 + e);
    int4 q1 = *(const int4*)(csr2 + e + 2);
    uint2 h0 = *(const uint2*)(h + (size_t)q0.x * NFEAT + c);
    uint2 h1 = *(const uint2*)(h + (size_t)q0.z * NFEAT + c);
    uint2 h2 = *(const uint2*)(h + (size_t)q1.x * NFEAT + c);
    uint2 h3 = *(const uint2*)(h + (size_t)q1.z * NFEAT + c);
    float w0 = __int_as_float(q0.y), w1 = __int_as_float(q0.w);
    float w2 = __int_as_float(q1.y), w3 = __int_as_float(q1.w);
    a0 = fmaf(w0, __uint_as_float(h0.x << 16), a0);
    a1 = fmaf(w0, __uint_as_float(h0.x & 0xffff0000u), a1);
    a2 = fmaf(w0, __uint_as_float(h0.y << 16), a2);
    a3 = fmaf(w0, __uint_as_float(h0.y & 0xffff0000u), a3);
    a0 = fmaf(w1, __uint_as_float(h1.x << 16), a0);
    a1 = fmaf(w1, __uint_as_float(h1.x & 0xffff0000u), a1);
    a2 = fmaf(w1, __uint_as_float(h1.y << 16), a2);
    a3 = fmaf(w1, __uint_as_float(h1.y & 0xffff0000u), a3);
    a0 = fmaf(w2, __uint_as_float(h2.x << 16), a0);
    a1 = fmaf(w2, __uint_as_float(h2.x & 0xffff0000u), a1);
    a2 = fmaf(w2, __uint_as_float(h2.y << 16), a2);
    a3 = fmaf(w2, __uint_as_float(h2.y & 0xffff0000u), a3);
    a0 = fmaf(w3, __uint_as_float(h3.x << 16), a0);
    a1 = fmaf(w3, __uint_as_float(h3.x & 0xffff0000u), a1);
    a2 = fmaf(w3, __uint_as_float(h3.y << 16), a2);
    a3 = fmaf(w3, __uint_as_float(h3.y & 0xffff0000u), a3);
  }
}

// both weights, transpose + cast; grid 128
__global__ __launch_bounds__(256) void k_cast_w(const float* __restrict__ W1,
                                                const float* __restrict__ W2,
                                                ushort* __restrict__ WT1,
                                                ushort* __restrict__ WT2) {
  int b = blockIdx.x;
  const float* W = (b < 64) ? W1 : W2;
  ushort* WT = (b < 64) ? WT1 : WT2;
  int idx = (b & 63) * 256 + threadIdx.x;
  int k = idx >> 7, nn = idx & 127;
  WT[nn * 128 + k] = f2b(W[idx]);
}

// ---------------- k_par1: gemm1 (fp32 A) PARALLEL WITH hist ----------------
// blockIdx < gemmBlocks: gemm1 x@W1 -> h1 (bf16). Else: XCD-partitioned dst
// histogram (sub-blocks stride-8 => constant XCD per node-range). Independent
// work merged into one dispatch to overlap HBM-bound gemm with atomic-bound hist.

__global__ __launch_bounds__(256) void k_par1(const float* __restrict__ x,
                                              const ushort* __restrict__ WT1,
                                              ushort* __restrict__ h1, int n,
                                              const int* __restrict__ dst,
                                              int* __restrict__ cnt, int E,
                                              int gemmBlocks) {
  if ((int)blockIdx.x >= gemmBlocks) {
    int bid = blockIdx.x - gemmBlocks;
    int range = bid & 7, chunk = bid >> 3;
    int lo = (int)(((long long)range * n) >> 3);
    int hi = (int)(((long long)(range + 1) * n) >> 3);
    int i = chunk * 1024 + threadIdx.x * 4;
    if (i + 3 < E) {
      int4 d4 = *(const int4*)(dst + i);
      if ((unsigned)(d4.x - lo) < (unsigned)(hi - lo)) atomicAdd(&cnt[d4.x], 1);
      if ((unsigned)(d4.y - lo) < (unsigned)(hi - lo)) atomicAdd(&cnt[d4.y], 1);
      if ((unsigned)(d4.z - lo) < (unsigned)(hi - lo)) atomicAdd(&cnt[d4.z], 1);
      if ((unsigned)(d4.w - lo) < (unsigned)(hi - lo)) atomicAdd(&cnt[d4.w], 1);
    } else {
      for (int j = 0; j < 4; j++) {
        if (i + j < E) {
          int d = dst[i + j];
          if ((unsigned)(d - lo) < (unsigned)(hi - lo)) atomicAdd(&cnt[d], 1);
        }
      }
    }
    return;
  }
  // ---- gemm1 branch ----
  __shared__ ushort sW[128][136];  // pad 136: ds_read_b128 -> 2-way bank = free
  int tid = threadIdx.x;
  {
    int r = tid >> 1, hh = tid & 1;
    const uint4* srcp = (const uint4*)(WT1 + r * 128 + hh * 64);
    uint4* dstp = (uint4*)(&sW[r][hh * 64]);
#pragma unroll
    for (int j = 0; j < 8; j++) dstp[j] = srcp[j];
  }
  __syncthreads();

  int wave = tid >> 6;
  int lane = tid & 63;
  int l16 = lane & 15;
  int quad = lane >> 4;
  int rowBase = blockIdx.x * 128 + wave * 32;

  bf16x8 afrag[2][4];
#pragma unroll
  for (int rt = 0; rt < 2; rt++) {
    int row = rowBase + rt * 16 + l16;
    row = min(row, n - 1);  // OOB rows compute garbage, never stored
    const float* Ap = x + (size_t)row * NFEAT + quad * 8;
#pragma unroll
    for (int ks = 0; ks < 4; ks++) {
      float4 f0 = *(const float4*)(Ap + ks * 32);
      float4 f1 = *(const float4*)(Ap + ks * 32 + 4);
      ushort t[8] = {f2b(f0.x), f2b(f0.y), f2b(f0.z), f2b(f0.w),
                     f2b(f1.x), f2b(f1.y), f2b(f1.z), f2b(f1.w)};
      afrag[rt][ks] = *(const bf16x8*)t;
    }
  }

#pragma unroll
  for (int ct = 0; ct < 8; ct++) {
    bf16x8 bfrag[4];
#pragma unroll
    for (int ks = 0; ks < 4; ks++)
      bfrag[ks] = *(const bf16x8*)(&sW[ct * 16 + l16][ks * 32 + quad * 8]);
    f32x4 acc[2] = {{0.f, 0.f, 0.f, 0.f}, {0.f, 0.f, 0.f, 0.f}};
#pragma unroll
    for (int rt = 0; rt < 2; rt++)
#pragma unroll
      for (int ks = 0; ks < 4; ks++)
        acc[rt] = __builtin_amdgcn_mfma_f32_16x16x32_bf16(afrag[rt][ks], bfrag[ks],
                                                          acc[rt], 0, 0, 0);
#pragma unroll
    for (int rt = 0; rt < 2; rt++)
#pragma unroll
      for (int r = 0; r < 4; r++) {
        int row = rowBase + rt * 16 + quad * 4 + r;
        if (row < n) h1[(size_t)row * NFEAT + ct * 16 + l16] = f2b(acc[rt][r]);
      }
  }
}

// scan of PADDED counts ceil((cnt+1)/4)*4 (self entry + pad-to-4); dinv fused.
__global__ __launch_bounds__(256) void k_scan_blocks(const int* __restrict__ cnt,
                                                     int* __restrict__ rowptr,
                                                     int* __restrict__ bsum,
                                                     float* __restrict__ dinv, int n) {
  __shared__ int s[256];
  int tid = threadIdx.x;
  int idx = blockIdx.x * 1024 + tid * 4;
  int v[4];
  int sum = 0;
#pragma unroll
  for (int j = 0; j < 4; j++) {
    int c = 0;
    if (idx + j < n) {
      c = cnt[idx + j];
      dinv[idx + j] = rsqrtf((float)(c + 1));
    }
    v[j] = (idx + j < n) ? ((c + 4) & ~3) : 0;  // ceil((c+1)/4)*4
    sum += v[j];
  }
  s[tid] = sum;
  __syncthreads();
  for (int off = 1; off < 256; off <<= 1) {
    int t = (tid >= off) ? s[tid - off] : 0;
    __syncthreads();
    s[tid] += t;
    __syncthreads();
  }
  if (tid == 255) bsum[blockIdx.x] = s[255];
  int run = s[tid] - sum;
#pragma unroll
  for (int j = 0; j < 4; j++) {
    if (idx + j < n) rowptr[idx + j] = run;
    run += v[j];
  }
}

// XCD-remapped finalize: blocks use the same range/chunk partition as hist/scatter
// so cursor init + self-entry csr2 writes stay in the home XCD's L2 (no write-amp).
__global__ __launch_bounds__(256) void k_scan_addcur(int* __restrict__ rowptr,
                                                     const int* __restrict__ bsum,
                                                     int* __restrict__ cursor,
                                                     const float* __restrict__ dinv,
                                                     int2* __restrict__ csr2,
                                                     int n, int nb) {
  __shared__ int s[256];
  int tid = threadIdx.x;
  int v = (tid < nb) ? bsum[tid] : 0;
  s[tid] = v;
  __syncthreads();
  for (int off = 1; off < 256; off <<= 1) {
    int t = (tid >= off) ? s[tid - off] : 0;
    __syncthreads();
    s[tid] += t;
    __syncthreads();
  }
  int total = s[255];
  __syncthreads();
  int ex = s[tid] - v;
  __syncthreads();
  s[tid] = ex;
  __syncthreads();
  int range = blockIdx.x & 7, chunk = blockIdx.x >> 3;
  int lo = (int)(((long long)range * n) >> 3);
  int hi = (int)(((long long)(range + 1) * n) >> 3);
  int i = lo + chunk * 256 + tid;
  if (i < hi) {
    int rp = rowptr[i] + s[i >> 10];
    rowptr[i] = rp;
    cursor[i] = rp + 1;  // slot 0 = self loop
    int2 self;
    self.x = i;
    self.y = __float_as_int(dinv[i]);
    csr2[rp] = self;
  }
  if (blockIdx.x == 0 && tid == 0) rowptr[n] = total;
}

__global__ __launch_bounds__(256) void k_scatter(const int* __restrict__ src,
                                                 const int* __restrict__ dst,
                                                 const float* __restrict__ dinv,
                                                 int* __restrict__ cursor,
                                                 int2* __restrict__ csr2, int E, int N) {
  int range = blockIdx.x & 7, chunk = blockIdx.x >> 3;
  int lo = (int)(((long long)range * N) >> 3);
  int hi = (int)(((long long)(range + 1) * N) >> 3);
  int i = chunk * 1024 + threadIdx.x * 4;
  if (i + 3 < E) {
    int4 d4 = *(const int4*)(dst + i);
    int4 s4 = *(const int4*)(src + i);
    int dd[4] = {d4.x, d4.y, d4.z, d4.w};
    int ss[4] = {s4.x, s4.y, s4.z, s4.w};
#pragma unroll
    for (int j = 0; j < 4; j++) {
      if ((unsigned)(dd[j] - lo) < (unsigned)(hi - lo)) {
        int p = atomicAdd(&cursor[dd[j]], 1);
        int2 v;
        v.x = ss[j];
        v.y = __float_as_int(dinv[ss[j]]);
        csr2[p] = v;
      }
    }
  } else {
    for (int j = 0; j < 4; j++) {
      if (i + j < E) {
        int d = dst[i + j];
        if ((unsigned)(d - lo) < (unsigned)(hi - lo)) {
          int s = src[i + j];
          int p = atomicAdd(&cursor[d], 1);
          int2 v;
          v.x = s;
          v.y = __float_as_int(dinv[s]);
          csr2[p] = v;
        }
      }
    }
  }
}

// ---------------- k_fused: agg1 (+b1, relu) -> LDS -> gemm2 -> h2 ----------------
// 64 nodes/block. Agg phase: 8 nodes in parallel (32 lanes each), results packed
// bf16 into sT. GEMM phase: 4 waves x 16 rows MFMA vs W2 (LDS). Deletes the t1
// global round-trip. LDS 52 KB -> 3 blocks/CU.

__global__ __launch_bounds__(256) void k_fused(const ushort* __restrict__ h1,
                                               const float* __restrict__ dinv,
                                               const int* __restrict__ rowptr,
                                               const int2* __restrict__ csr2,
                                               const float* __restrict__ b1,
                                               const ushort* __restrict__ WT2,
                                               ushort* __restrict__ h2, int n) {
  __shared__ ushort sW[128][136];
  __shared__ ushort sT[64][136];
  int tid = threadIdx.x;
  {
    int r = tid >> 1, hh = tid & 1;
    const uint4* srcp = (const uint4*)(WT2 + r * 128 + hh * 64);
    uint4* dstp = (uint4*)(&sW[r][hh * 64]);
#pragma unroll
    for (int j = 0; j < 8; j++) dstp[j] = srcp[j];
  }

  int base = blockIdx.x * 64;
  int c = (tid & 31) * 4;
#pragma unroll 1
  for (int batch = 0; batch < 8; batch++) {
    int nl = batch * 8 + (tid >> 5);
    int node = base + nl;
    if (node < n) {
      float a0 = 0.f, a1 = 0.f, a2 = 0.f, a3 = 0.f;
      agg_accum(h1, csr2, rowptr[node], rowptr[node + 1], c, a0, a1, a2, a3);
      float di = dinv[node];
      float4 bb = *(const float4*)(b1 + c);
      float o0 = fmaxf(fmaf(di, a0, bb.x), 0.f);
      float o1 = fmaxf(fmaf(di, a1, bb.y), 0.f);
      float o2 = fmaxf(fmaf(di, a2, bb.z), 0.f);
      float o3 = fmaxf(fmaf(di, a3, bb.w), 0.f);
      uint2 pk;
      pk.x = f2b(o0) | ((unsigned)f2b(o1) << 16);
      pk.y = f2b(o2) | ((unsigned)f2b(o3) << 16);
      *(uint2*)(&sT[nl][c]) = pk;
    }
  }
  __syncthreads();

  // gemm phase: wave w owns rows w*16..w*16+15 of the 64-row tile
  int wave = tid >> 6;
  int lane = tid & 63;
  int l16 = lane & 15;
  int quad = lane >> 4;
  bf16x8 afrag[4];
#pragma unroll
  for (int ks = 0; ks < 4; ks++)
    afrag[ks] = *(const bf16x8*)(&sT[wave * 16 + l16][ks * 32 + quad * 8]);

#pragma unroll
  for (int ct = 0; ct < 8; ct++) {
    bf16x8 bfrag[4];
#pragma unroll
    for (int ks = 0; ks < 4; ks++)
      bfrag[ks] = *(const bf16x8*)(&sW[ct * 16 + l16][ks * 32 + quad * 8]);
    f32x4 acc = {0.f, 0.f, 0.f, 0.f};
#pragma unroll
    for (int ks = 0; ks < 4; ks++)
      acc = __builtin_amdgcn_mfma_f32_16x16x32_bf16(afrag[ks], bfrag[ks], acc, 0, 0, 0);
#pragma unroll
    for (int r = 0; r < 4; r++) {
      int row = base + wave * 16 + quad * 4 + r;
      if (row < n) h2[(size_t)row * NFEAT + ct * 16 + l16] = f2b(acc[r]);
    }
  }
}

// ---------------- agg2: 32 lanes/node, 2 nodes/wave, fp32 out ----------------

__global__ __launch_bounds__(256) void k_agg2(const ushort* __restrict__ h,
                                              const float* __restrict__ dinv,
                                              const int* __restrict__ rowptr,
                                              const int2* __restrict__ csr2,
                                              const float* __restrict__ bias,
                                              float* __restrict__ out, int n) {
  int node = blockIdx.x * 8 + (threadIdx.x >> 5);
  if (node >= n) return;
  int c = (threadIdx.x & 31) * 4;
  float a0 = 0.f, a1 = 0.f, a2 = 0.f, a3 = 0.f;
  agg_accum(h, csr2, rowptr[node], rowptr[node + 1], c, a0, a1, a2, a3);
  float di = dinv[node];
  float4 b = *(const float4*)(bias + c);
  float4 o;
  o.x = fmaf(di, a0, b.x);
  o.y = fmaf(di, a1, b.y);
  o.z = fmaf(di, a2, b.z);
  o.w = fmaf(di, a3, b.w);
  *(float4*)(out + (size_t)node * NFEAT + c) = o;
}

// ---------------- launch ----------------

extern "C" void kernel_launch(void* const* d_in, const int* in_sizes, int n_in,
                              void* d_out, int out_size, void* d_ws, size_t ws_size,
                              hipStream_t stream) {
  const float* x = (const float*)d_in[0];
  const float* W1 = (const float*)d_in[1];
  const float* b1 = (const float*)d_in[2];
  const float* W2 = (const float*)d_in[3];
  const float* b2 = (const float*)d_in[4];
  const int* ei = (const int*)d_in[5];

  const int N = in_sizes[0] / NFEAT;
  const int E = in_sizes[5] / 2;
  const int* srcIdx = ei;
  const int* dstIdx = ei + E;

  char* p = (char*)d_ws;
  auto alloc = [&](size_t bytes) {
    char* r = p;
    p += (bytes + 255) & ~(size_t)255;
    return r;
  };
  // cnt and csr2 adjacent -> single memset zeroes counts AND pad entries
  int* cnt = (int*)alloc((size_t)N * 4);
  int2* csr2 = (int2*)alloc((size_t)(E + 4 * N + 16) * 8);  // self + pad-to-4
  char* memset_end = p;
  int* cursor = (int*)alloc((size_t)N * 4);
  float* dinv = (float*)alloc((size_t)N * 4);
  int* rowptr = (int*)alloc((size_t)(N + 1) * 4);
  int* bsum = (int*)alloc(1024);
  ushort* WT1 = (ushort*)alloc(NFEAT * NFEAT * 2);
  ushort* WT2 = (ushort*)alloc(NFEAT * NFEAT * 2);
  ushort* h2 = (ushort*)alloc((size_t)N * NFEAT * 2);  // gemm2 out (bf16)
  ushort* h1 = (ushort*)d_out;  // gemm1 out in d_out; dead before agg2 writes
  float* out = (float*)d_out;

  hipMemsetAsync(cnt, 0, (size_t)(memset_end - (char*)cnt), stream);

  int nb = (N + 1023) / 1024;
  int gEx = ((E + 1023) / 1024) * 8;   // XCD-partitioned edge blocks
  int gG1 = (N + 127) / 128;           // gemm1 blocks
  int cpr = (((N + 7) / 8) + 255) / 256;  // chunks per node-range

  k_cast_w<<<128, 256, 0, stream>>>(W1, W2, WT1, WT2);
  k_par1<<<gG1 + gEx, 256, 0, stream>>>(x, WT1, h1, N, dstIdx, cnt, E, gG1);
  k_scan_blocks<<<nb, 256, 0, stream>>>(cnt, rowptr, bsum, dinv, N);
  k_scan_addcur<<<8 * cpr, 256, 0, stream>>>(rowptr, bsum, cursor, dinv, csr2, N, nb);
  k_scatter<<<gEx, 256, 0, stream>>>(srcIdx, dstIdx, dinv, cursor, csr2, E, N);
  k_fused<<<(N + 63) / 64, 256, 0, stream>>>(h1, dinv, rowptr, csr2, b1, WT2, h2, N);
  k_agg2<<<(N + 7) / 8, 256, 0, stream>>>(h2, dinv, rowptr, csr2, b2, out, N);
}

// Round 7
// 251.586 us; speedup vs baseline: 1.0985x; 1.0985x over previous
//
#include <hip/hip_runtime.h>

#define NFEAT 128

typedef __attribute__((ext_vector_type(8))) short bf16x8;
typedef __attribute__((ext_vector_type(4))) float f32x4;

__device__ inline ushort f2b(float v) {  // fp32 -> bf16 RNE
  unsigned u = __builtin_bit_cast(unsigned, v);
  return (ushort)((u + 0x7FFFu + ((u >> 16) & 1u)) >> 16);
}

// agg inner loop: unroll-4 over padded CSR segment (pads are (0, w=0.0))
__device__ inline void agg_accum(const ushort* __restrict__ h,
                                 const int2* __restrict__ csr2, int e, int end, int c,
                                 float& a0, float& a1, float& a2, float& a3) {
  for (; e < end; e += 4) {
    int4 q0 = *(const int4*)(csr2 + e);
    int4 q1 = *(const int4*)(csr2 + e + 2);
    uint2 h0 = *(const uint2*)(h + (size_t)q0.x * NFEAT + c);
    uint2 h1 = *(const uint2*)(h + (size_t)q0.z * NFEAT + c);
    uint2 h2 = *(const uint2*)(h + (size_t)q1.x * NFEAT + c);
    uint2 h3 = *(const uint2*)(h + (size_t)q1.z * NFEAT + c);
    float w0 = __int_as_float(q0.y), w1 = __int_as_float(q0.w);
    float w2 = __int_as_float(q1.y), w3 = __int_as_float(q1.w);
    a0 = fmaf(w0, __uint_as_float(h0.x << 16), a0);
    a1 = fmaf(w0, __uint_as_float(h0.x & 0xffff0000u), a1);
    a2 = fmaf(w0, __uint_as_float(h0.y << 16), a2);
    a3 = fmaf(w0, __uint_as_float(h0.y & 0xffff0000u), a3);
    a0 = fmaf(w1, __uint_as_float(h1.x << 16), a0);
    a1 = fmaf(w1, __uint_as_float(h1.x & 0xffff0000u), a1);
    a2 = fmaf(w1, __uint_as_float(h1.y << 16), a2);
    a3 = fmaf(w1, __uint_as_float(h1.y & 0xffff0000u), a3);
    a0 = fmaf(w2, __uint_as_float(h2.x << 16), a0);
    a1 = fmaf(w2, __uint_as_float(h2.x & 0xffff0000u), a1);
    a2 = fmaf(w2, __uint_as_float(h2.y << 16), a2);
    a3 = fmaf(w2, __uint_as_float(h2.y & 0xffff0000u), a3);
    a0 = fmaf(w3, __uint_as_float(h3.x << 16), a0);
    a1 = fmaf(w3, __uint_as_float(h3.x & 0xffff0000u), a1);
    a2 = fmaf(w3, __uint_as_float(h3.y << 16), a2);
    a3 = fmaf(w3, __uint_as_float(h3.y & 0xffff0000u), a3);
  }
}

// both weights, transpose + cast; grid 128
__global__ __launch_bounds__(256) void k_cast_w(const float* __restrict__ W1,
                                                const float* __restrict__ W2,
                                                ushort* __restrict__ WT1,
                                                ushort* __restrict__ WT2) {
  int b = blockIdx.x;
  const float* W = (b < 64) ? W1 : W2;
  ushort* WT = (b < 64) ? WT1 : WT2;
  int idx = (b & 63) * 256 + threadIdx.x;
  int k = idx >> 7, nn = idx & 127;
  WT[nn * 128 + k] = f2b(W[idx]);
}

// ---------------- k_par1: gemm1 (fp32 A) PARALLEL WITH hist ----------------
// blockIdx < gemmBlocks: gemm1 x@W1 -> h1 (bf16). Else: XCD-partitioned dst
// histogram. Independent work merged to overlap HBM-bound gemm with atomics.

__global__ __launch_bounds__(256) void k_par1(const float* __restrict__ x,
                                              const ushort* __restrict__ WT1,
                                              ushort* __restrict__ h1, int n,
                                              const int* __restrict__ dst,
                                              int* __restrict__ cnt, int E,
                                              int gemmBlocks) {
  if ((int)blockIdx.x >= gemmBlocks) {
    int bid = blockIdx.x - gemmBlocks;
    int range = bid & 7, chunk = bid >> 3;
    int lo = (int)(((long long)range * n) >> 3);
    int hi = (int)(((long long)(range + 1) * n) >> 3);
    int i = chunk * 1024 + threadIdx.x * 4;
    if (i + 3 < E) {
      int4 d4 = *(const int4*)(dst + i);
      if ((unsigned)(d4.x - lo) < (unsigned)(hi - lo)) atomicAdd(&cnt[d4.x], 1);
      if ((unsigned)(d4.y - lo) < (unsigned)(hi - lo)) atomicAdd(&cnt[d4.y], 1);
      if ((unsigned)(d4.z - lo) < (unsigned)(hi - lo)) atomicAdd(&cnt[d4.z], 1);
      if ((unsigned)(d4.w - lo) < (unsigned)(hi - lo)) atomicAdd(&cnt[d4.w], 1);
    } else {
      for (int j = 0; j < 4; j++) {
        if (i + j < E) {
          int d = dst[i + j];
          if ((unsigned)(d - lo) < (unsigned)(hi - lo)) atomicAdd(&cnt[d], 1);
        }
      }
    }
    return;
  }
  // ---- gemm1 branch ----
  __shared__ ushort sW[128][136];  // pad 136: ds_read_b128 -> 2-way bank = free
  int tid = threadIdx.x;
  {
    int r = tid >> 1, hh = tid & 1;
    const uint4* srcp = (const uint4*)(WT1 + r * 128 + hh * 64);
    uint4* dstp = (uint4*)(&sW[r][hh * 64]);
#pragma unroll
    for (int j = 0; j < 8; j++) dstp[j] = srcp[j];
  }
  __syncthreads();

  int wave = tid >> 6;
  int lane = tid & 63;
  int l16 = lane & 15;
  int quad = lane >> 4;
  int rowBase = blockIdx.x * 128 + wave * 32;

  bf16x8 afrag[2][4];
#pragma unroll
  for (int rt = 0; rt < 2; rt++) {
    int row = rowBase + rt * 16 + l16;
    row = min(row, n - 1);  // OOB rows compute garbage, never stored
    const float* Ap = x + (size_t)row * NFEAT + quad * 8;
#pragma unroll
    for (int ks = 0; ks < 4; ks++) {
      float4 f0 = *(const float4*)(Ap + ks * 32);
      float4 f1 = *(const float4*)(Ap + ks * 32 + 4);
      ushort t[8] = {f2b(f0.x), f2b(f0.y), f2b(f0.z), f2b(f0.w),
                     f2b(f1.x), f2b(f1.y), f2b(f1.z), f2b(f1.w)};
      afrag[rt][ks] = *(const bf16x8*)t;
    }
  }

#pragma unroll
  for (int ct = 0; ct < 8; ct++) {
    bf16x8 bfrag[4];
#pragma unroll
    for (int ks = 0; ks < 4; ks++)
      bfrag[ks] = *(const bf16x8*)(&sW[ct * 16 + l16][ks * 32 + quad * 8]);
    f32x4 acc[2] = {{0.f, 0.f, 0.f, 0.f}, {0.f, 0.f, 0.f, 0.f}};
#pragma unroll
    for (int rt = 0; rt < 2; rt++)
#pragma unroll
      for (int ks = 0; ks < 4; ks++)
        acc[rt] = __builtin_amdgcn_mfma_f32_16x16x32_bf16(afrag[rt][ks], bfrag[ks],
                                                          acc[rt], 0, 0, 0);
#pragma unroll
    for (int rt = 0; rt < 2; rt++)
#pragma unroll
      for (int r = 0; r < 4; r++) {
        int row = rowBase + rt * 16 + quad * 4 + r;
        if (row < n) h1[(size_t)row * NFEAT + ct * 16 + l16] = f2b(acc[rt][r]);
      }
  }
}

// ---------------- standalone gemm2: t1[n,128] @ W2 -> h2 (bf16) ----------------

__global__ __launch_bounds__(256) void k_gemm2(const ushort* __restrict__ A,
                                               const ushort* __restrict__ WT,
                                               ushort* __restrict__ out, int n) {
  __shared__ ushort sW[128][136];
  int tid = threadIdx.x;
  {
    int r = tid >> 1, hh = tid & 1;
    const uint4* srcp = (const uint4*)(WT + r * 128 + hh * 64);
    uint4* dstp = (uint4*)(&sW[r][hh * 64]);
#pragma unroll
    for (int j = 0; j < 8; j++) dstp[j] = srcp[j];
  }
  __syncthreads();

  int wave = tid >> 6;
  int lane = tid & 63;
  int l16 = lane & 15;
  int quad = lane >> 4;
  int rowBase = blockIdx.x * 128 + wave * 32;

  bf16x8 afrag[2][4];
#pragma unroll
  for (int rt = 0; rt < 2; rt++) {
    int row = rowBase + rt * 16 + l16;
    row = min(row, n - 1);
    const ushort* Ap = A + (size_t)row * NFEAT + quad * 8;
#pragma unroll
    for (int ks = 0; ks < 4; ks++) afrag[rt][ks] = *(const bf16x8*)(Ap + ks * 32);
  }

#pragma unroll
  for (int ct = 0; ct < 8; ct++) {
    bf16x8 bfrag[4];
#pragma unroll
    for (int ks = 0; ks < 4; ks++)
      bfrag[ks] = *(const bf16x8*)(&sW[ct * 16 + l16][ks * 32 + quad * 8]);
    f32x4 acc[2] = {{0.f, 0.f, 0.f, 0.f}, {0.f, 0.f, 0.f, 0.f}};
#pragma unroll
    for (int rt = 0; rt < 2; rt++)
#pragma unroll
      for (int ks = 0; ks < 4; ks++)
        acc[rt] = __builtin_amdgcn_mfma_f32_16x16x32_bf16(afrag[rt][ks], bfrag[ks],
                                                          acc[rt], 0, 0, 0);
#pragma unroll
    for (int rt = 0; rt < 2; rt++)
#pragma unroll
      for (int r = 0; r < 4; r++) {
        int row = rowBase + rt * 16 + quad * 4 + r;
        if (row < n) out[(size_t)row * NFEAT + ct * 16 + l16] = f2b(acc[rt][r]);
      }
  }
}

// scan of PADDED counts ceil((cnt+1)/4)*4 (self entry + pad-to-4); dinv fused.
__global__ __launch_bounds__(256) void k_scan_blocks(const int* __restrict__ cnt,
                                                     int* __restrict__ rowptr,
                                                     int* __restrict__ bsum,
                                                     float* __restrict__ dinv, int n) {
  __shared__ int s[256];
  int tid = threadIdx.x;
  int idx = blockIdx.x * 1024 + tid * 4;
  int v[4];
  int sum = 0;
#pragma unroll
  for (int j = 0; j < 4; j++) {
    int c = 0;
    if (idx + j < n) {
      c = cnt[idx + j];
      dinv[idx + j] = rsqrtf((float)(c + 1));
    }
    v[j] = (idx + j < n) ? ((c + 4) & ~3) : 0;  // ceil((c+1)/4)*4
    sum += v[j];
  }
  s[tid] = sum;
  __syncthreads();
  for (int off = 1; off < 256; off <<= 1) {
    int t = (tid >= off) ? s[tid - off] : 0;
    __syncthreads();
    s[tid] += t;
    __syncthreads();
  }
  if (tid == 255) bsum[blockIdx.x] = s[255];
  int run = s[tid] - sum;
#pragma unroll
  for (int j = 0; j < 4; j++) {
    if (idx + j < n) rowptr[idx + j] = run;
    run += v[j];
  }
}

// XCD-remapped finalize: same range/chunk partition as hist/scatter so cursor
// init + self-entry csr2 writes stay in the home XCD's L2.
__global__ __launch_bounds__(256) void k_scan_addcur(int* __restrict__ rowptr,
                                                     const int* __restrict__ bsum,
                                                     int* __restrict__ cursor,
                                                     const float* __restrict__ dinv,
                                                     int2* __restrict__ csr2,
                                                     int n, int nb) {
  __shared__ int s[256];
  int tid = threadIdx.x;
  int v = (tid < nb) ? bsum[tid] : 0;
  s[tid] = v;
  __syncthreads();
  for (int off = 1; off < 256; off <<= 1) {
    int t = (tid >= off) ? s[tid - off] : 0;
    __syncthreads();
    s[tid] += t;
    __syncthreads();
  }
  int total = s[255];
  __syncthreads();
  int ex = s[tid] - v;
  __syncthreads();
  s[tid] = ex;
  __syncthreads();
  int range = blockIdx.x & 7, chunk = blockIdx.x >> 3;
  int lo = (int)(((long long)range * n) >> 3);
  int hi = (int)(((long long)(range + 1) * n) >> 3);
  int i = lo + chunk * 256 + tid;
  if (i < hi) {
    int rp = rowptr[i] + s[i >> 10];
    rowptr[i] = rp;
    cursor[i] = rp + 1;  // slot 0 = self loop
    int2 self;
    self.x = i;
    self.y = __float_as_int(dinv[i]);
    csr2[rp] = self;
  }
  if (blockIdx.x == 0 && tid == 0) rowptr[n] = total;
}

__global__ __launch_bounds__(256) void k_scatter(const int* __restrict__ src,
                                                 const int* __restrict__ dst,
                                                 const float* __restrict__ dinv,
                                                 int* __restrict__ cursor,
                                                 int2* __restrict__ csr2, int E, int N) {
  int range = blockIdx.x & 7, chunk = blockIdx.x >> 3;
  int lo = (int)(((long long)range * N) >> 3);
  int hi = (int)(((long long)(range + 1) * N) >> 3);
  int i = chunk * 1024 + threadIdx.x * 4;
  if (i + 3 < E) {
    int4 d4 = *(const int4*)(dst + i);
    int4 s4 = *(const int4*)(src + i);
    int dd[4] = {d4.x, d4.y, d4.z, d4.w};
    int ss[4] = {s4.x, s4.y, s4.z, s4.w};
#pragma unroll
    for (int j = 0; j < 4; j++) {
      if ((unsigned)(dd[j] - lo) < (unsigned)(hi - lo)) {
        int p = atomicAdd(&cursor[dd[j]], 1);
        int2 v;
        v.x = ss[j];
        v.y = __float_as_int(dinv[ss[j]]);
        csr2[p] = v;
      }
    }
  } else {
    for (int j = 0; j < 4; j++) {
      if (i + j < E) {
        int d = dst[i + j];
        if ((unsigned)(d - lo) < (unsigned)(hi - lo)) {
          int s = src[i + j];
          int p = atomicAdd(&cursor[d], 1);
          int2 v;
          v.x = s;
          v.y = __float_as_int(dinv[s]);
          csr2[p] = v;
        }
      }
    }
  }
}

// ---------------- agg1: bf16 out + bias + relu; 32 lanes/node ----------------

__global__ __launch_bounds__(256) void k_agg1(const ushort* __restrict__ h,
                                              const float* __restrict__ dinv,
                                              const int* __restrict__ rowptr,
                                              const int2* __restrict__ csr2,
                                              const float* __restrict__ bias,
                                              ushort* __restrict__ out, int n) {
  int node = blockIdx.x * 8 + (threadIdx.x >> 5);
  if (node >= n) return;
  int c = (threadIdx.x & 31) * 4;
  float a0 = 0.f, a1 = 0.f, a2 = 0.f, a3 = 0.f;
  agg_accum(h, csr2, rowptr[node], rowptr[node + 1], c, a0, a1, a2, a3);
  float di = dinv[node];
  float4 b = *(const float4*)(bias + c);
  float o0 = fmaxf(fmaf(di, a0, b.x), 0.f);
  float o1 = fmaxf(fmaf(di, a1, b.y), 0.f);
  float o2 = fmaxf(fmaf(di, a2, b.z), 0.f);
  float o3 = fmaxf(fmaf(di, a3, b.w), 0.f);
  uint2 pk;
  pk.x = f2b(o0) | ((unsigned)f2b(o1) << 16);
  pk.y = f2b(o2) | ((unsigned)f2b(o3) << 16);
  *(uint2*)(out + (size_t)node * NFEAT + c) = pk;
}

// ---------------- agg2: fp32 out + bias; 32 lanes/node ----------------

__global__ __launch_bounds__(256) void k_agg2(const ushort* __restrict__ h,
                                              const float* __restrict__ dinv,
                                              const int* __restrict__ rowptr,
                                              const int2* __restrict__ csr2,
                                              const float* __restrict__ bias,
                                              float* __restrict__ out, int n) {
  int node = blockIdx.x * 8 + (threadIdx.x >> 5);
  if (node >= n) return;
  int c = (threadIdx.x & 31) * 4;
  float a0 = 0.f, a1 = 0.f, a2 = 0.f, a3 = 0.f;
  agg_accum(h, csr2, rowptr[node], rowptr[node + 1], c, a0, a1, a2, a3);
  float di = dinv[node];
  float4 b = *(const float4*)(bias + c);
  float4 o;
  o.x = fmaf(di, a0, b.x);
  o.y = fmaf(di, a1, b.y);
  o.z = fmaf(di, a2, b.z);
  o.w = fmaf(di, a3, b.w);
  *(float4*)(out + (size_t)node * NFEAT + c) = o;
}

// ---------------- launch ----------------

extern "C" void kernel_launch(void* const* d_in, const int* in_sizes, int n_in,
                              void* d_out, int out_size, void* d_ws, size_t ws_size,
                              hipStream_t stream) {
  const float* x = (const float*)d_in[0];
  const float* W1 = (const float*)d_in[1];
  const float* b1 = (const float*)d_in[2];
  const float* W2 = (const float*)d_in[3];
  const float* b2 = (const float*)d_in[4];
  const int* ei = (const int*)d_in[5];

  const int N = in_sizes[0] / NFEAT;
  const int E = in_sizes[5] / 2;
  const int* srcIdx = ei;
  const int* dstIdx = ei + E;

  char* p = (char*)d_ws;
  auto alloc = [&](size_t bytes) {
    char* r = p;
    p += (bytes + 255) & ~(size_t)255;
    return r;
  };
  // cnt and csr2 adjacent -> single memset zeroes counts AND pad entries
  int* cnt = (int*)alloc((size_t)N * 4);
  int2* csr2 = (int2*)alloc((size_t)(E + 4 * N + 16) * 8);  // self + pad-to-4
  char* memset_end = p;
  int* cursor = (int*)alloc((size_t)N * 4);
  float* dinv = (float*)alloc((size_t)N * 4);
  int* rowptr = (int*)alloc((size_t)(N + 1) * 4);
  int* bsum = (int*)alloc(1024);
  ushort* WT1 = (ushort*)alloc(NFEAT * NFEAT * 2);
  ushort* WT2 = (ushort*)alloc(NFEAT * NFEAT * 2);
  ushort* t1 = (ushort*)alloc((size_t)N * NFEAT * 2);  // agg1 out (bf16)
  ushort* h2 = (ushort*)alloc((size_t)N * NFEAT * 2);  // gemm2 out (bf16)
  ushort* h1 = (ushort*)d_out;  // gemm1 out in d_out; dead before agg2 writes
  float* out = (float*)d_out;

  hipMemsetAsync(cnt, 0, (size_t)(memset_end - (char*)cnt), stream);

  int nb = (N + 1023) / 1024;
  int gEx = ((E + 1023) / 1024) * 8;      // XCD-partitioned edge blocks
  int gG = (N + 127) / 128;               // gemm blocks
  int cpr = (((N + 7) / 8) + 255) / 256;  // chunks per node-range

  k_cast_w<<<128, 256, 0, stream>>>(W1, W2, WT1, WT2);
  k_par1<<<gG + gEx, 256, 0, stream>>>(x, WT1, h1, N, dstIdx, cnt, E, gG);
  k_scan_blocks<<<nb, 256, 0, stream>>>(cnt, rowptr, bsum, dinv, N);
  k_scan_addcur<<<8 * cpr, 256, 0, stream>>>(rowptr, bsum, cursor, dinv, csr2, N, nb);
  k_scatter<<<gEx, 256, 0, stream>>>(srcIdx, dstIdx, dinv, cursor, csr2, E, N);
  k_agg1<<<(N + 7) / 8, 256, 0, stream>>>(h1, dinv, rowptr, csr2, b1, t1, N);
  k_gemm2<<<gG, 256, 0, stream>>>(t1, WT2, h2, N);
  k_agg2<<<(N + 7) / 8, 256, 0, stream>>>(h2, dinv, rowptr, csr2, b2, out, N);
}